// Round 9
// baseline (79.245 us; speedup 1.0000x reference)
//
#include <hip/hip_runtime.h>

#define HH 128
#define NN 64
#define LL 256

typedef __attribute__((ext_vector_type(8))) short bf8;
typedef __attribute__((ext_vector_type(4))) float f32x4;

__device__ inline ushort f2bf(float f) {
    uint x = __float_as_uint(f);
    return (ushort)((x + 0x7fffu + ((x >> 16) & 1u)) >> 16);
}
__device__ inline uint cvt_pk_bf16(float lo, float hi) {
    uint r;
    asm volatile("v_cvt_pk_bf16_f32 %0, %1, %2" : "=v"(r) : "v"(lo), "v"(hi));
    return r;
}
#define MFMA(a,b,c) __builtin_amdgcn_mfma_f32_16x16x32_bf16((a),(b),(c),0,0,0)

// Tap generation, hw trig, one block per (h, s). Packed pair-table out:
// arrg[(s*HH+h)*512 + i] = rev[i] | rev[i+1]<<16, rev[i] = kcat_s[h][511-i].
__global__ __launch_bounds__(512) void ssm_gen_fast(
    const float* __restrict__ A_re0, const float* __restrict__ A_im0,
    const float* __restrict__ C_re0, const float* __restrict__ C_im0,
    const float* __restrict__ log_dt0,
    const float* __restrict__ A_re1, const float* __restrict__ A_im1,
    const float* __restrict__ C_re1, const float* __restrict__ C_im1,
    const float* __restrict__ log_dt1,
    uint* __restrict__ arrg)
{
    __shared__ float4 par[128];     // (ch,n) -> {xr, xi_rev, Kr2, Ki2}
    __shared__ ushort rev[512];

    int tid = threadIdx.x;
    int h   = blockIdx.x;
    int s   = blockIdx.y;

    if (tid < 128) {
        int n  = tid & 63;
        int ch = tid >> 6;
        const float* Ar = s ? A_re1 : A_re0;
        const float* Ai = s ? A_im1 : A_im0;
        const float* Cr = s ? C_re1 : C_re0;
        const float* Ci = s ? C_im1 : C_im0;
        const float* Ld = s ? log_dt1 : log_dt0;
        float dt = __expf(Ld[h]);
        float ar = Ar[h*NN + n], ai = Ai[h*NN + n];
        float cr = Cr[(ch*HH + h)*NN + n], ci = Ci[(ch*HH + h)*NN + n];
        float xr = dt * ar, xi = dt * ai;
        float phr = xi * 0.15915494f;
        float phf = phr - floorf(phr);
        float sn = __sinf(6.2831853f * phf);
        float cs = __cosf(6.2831853f * phf);
        float e  = __expf(xr);
        float er = e*cs - 1.f, ei = e*sn;
        float inv = 1.f / (ar*ar + ai*ai);
        float dr = (er*ar + ei*ai) * inv;
        float di = (ei*ar - er*ai) * inv;
        float Kr = 2.f*(cr*dr - ci*di);
        float Ki = 2.f*(cr*di + ci*dr);
        par[tid] = (float4){ xr, xi * 0.15915494f, Kr, Ki };
    }
    __syncthreads();

    {
        int l  = tid & 255;
        int ch = tid >> 8;
        float lf = (float)l;
        int ri = ch ? (256 + l) : (255 - l);
        const float4* pb = &par[ch*64];
        float acc = 0.f;
        for (int n = 0; n < NN; ++n) {
            float4 p = pb[n];
            float mag = __expf(p.x * lf);
            float ph  = p.y * lf;
            float phf = ph - floorf(ph);
            float ang = 6.2831853f * phf;
            acc += p.z * (mag * __cosf(ang)) - p.w * (mag * __sinf(ang));
        }
        rev[ri] = f2bf(acc);
    }
    __syncthreads();

    uint lo = rev[tid];
    uint hi = (tid < 511) ? (uint)rev[tid + 1] : 0u;
    arrg[(s*HH + h)*512 + tid] = lo | (hi << 16);
}

// Fused S4ND per (b, h, y'-eighth): 256 threads / 4 waves, ~6 blocks/CU
// resident with 2048 queued -> natural stagger of phases across blocks.
// phase 1: WT[y'][x] = sum_y M2[y'][y]*U[x][y]  (acc in regs, WT in LDS)
// phase 2: Y[x'][y'] = sum_x M1[x'][x]*WT[y'][x] + D[h]*u -> global.
__global__ __launch_bounds__(256, 6) void s4nd_one(
    const float* __restrict__ u, const float* __restrict__ Dv,
    const uint* __restrict__ arrg, float* __restrict__ out)
{
    __shared__ ushort WT[32 * 256];       // 16384 B (XOR-swizzled cols)
    __shared__ uint   arr[2][512];        // 4096 B

    int tid = threadIdx.x;

    // XCD swizzle: all 8 eighth-blocks of a bh on the same XCD, adjacent.
    int j    = blockIdx.x;
    int xcd  = j & 7;
    int k    = j >> 3;                    // 0..255
    int bh   = xcd * 32 + (k >> 3);
    int yq   = (k & 7) * 32;              // y' slice offset
    int h    = bh & (HH - 1);

#pragma unroll
    for (int i = 0; i < 2; ++i) {
        arr[i][tid]       = arrg[(i*HH + h)*512 + tid];
        arr[i][tid + 256] = arrg[(i*HH + h)*512 + tid + 256];
    }
    __syncthreads();

    int lane = tid & 63;
    int w = tid >> 6;                 // 0..3
    int c = lane & 15, q = lane >> 4;

    f32x4 acc[8];
#pragma unroll
    for (int i = 0; i < 8; ++i) acc[i] = (f32x4){0.f,0.f,0.f,0.f};

    const float* ub = u + (size_t)bh * LL * LL;

    // ---- phase 1 (no barriers): wave w covers x in [w*64, w*64+64) ----
    // acc[mi*4+rr]: mi = y' 16-block (2), rr = x 16-block (4)
    {
        const float* rp0 = ub + (size_t)(w*64 +  0 + c) * LL;
        const float* rp1 = ub + (size_t)(w*64 + 16 + c) * LL;
        const float* rp2 = ub + (size_t)(w*64 + 32 + c) * LL;
        const float* rp3 = ub + (size_t)(w*64 + 48 + c) * LL;
#pragma unroll 2
        for (int kk = 0; kk < 8; ++kk) {
            int yb = kk*32 + 8*q;
            bf8 b0, b1, b2, b3;
            {   // group 1: rows 0,1 (limits live f32 regs)
                float4 f0a = *(const float4*)(rp0 + yb), f0b = *(const float4*)(rp0 + yb + 4);
                float4 f1a = *(const float4*)(rp1 + yb), f1b = *(const float4*)(rp1 + yb + 4);
                uint* p0 = (uint*)&b0; uint* p1 = (uint*)&b1;
                p0[0] = cvt_pk_bf16(f0a.x, f0a.y); p0[1] = cvt_pk_bf16(f0a.z, f0a.w);
                p0[2] = cvt_pk_bf16(f0b.x, f0b.y); p0[3] = cvt_pk_bf16(f0b.z, f0b.w);
                p1[0] = cvt_pk_bf16(f1a.x, f1a.y); p1[1] = cvt_pk_bf16(f1a.z, f1a.w);
                p1[2] = cvt_pk_bf16(f1b.x, f1b.y); p1[3] = cvt_pk_bf16(f1b.z, f1b.w);
            }
            {   // group 2: rows 2,3
                float4 f2a = *(const float4*)(rp2 + yb), f2b = *(const float4*)(rp2 + yb + 4);
                float4 f3a = *(const float4*)(rp3 + yb), f3b = *(const float4*)(rp3 + yb + 4);
                uint* p2 = (uint*)&b2; uint* p3 = (uint*)&b3;
                p2[0] = cvt_pk_bf16(f2a.x, f2a.y); p2[1] = cvt_pk_bf16(f2a.z, f2a.w);
                p2[2] = cvt_pk_bf16(f2b.x, f2b.y); p2[3] = cvt_pk_bf16(f2b.z, f2b.w);
                p3[0] = cvt_pk_bf16(f3a.x, f3a.y); p3[1] = cvt_pk_bf16(f3a.z, f3a.w);
                p3[2] = cvt_pk_bf16(f3b.x, f3b.y); p3[3] = cvt_pk_bf16(f3b.z, f3b.w);
            }
            int sbase = 255 - yq - c + kk*32 + 8*q;
            __builtin_amdgcn_s_setprio(1);
#pragma unroll
            for (int mi = 0; mi < 2; ++mi) {
                int s0 = sbase - 16*mi;   // a[jj] = M2[yq+16mi+c][kk*32+8q+jj]
                bf8 a; uint* pa = (uint*)&a;
                pa[0] = arr[1][s0];     pa[1] = arr[1][s0 + 2];
                pa[2] = arr[1][s0 + 4]; pa[3] = arr[1][s0 + 6];
                acc[mi*4 + 0] = MFMA(a, b0, acc[mi*4 + 0]);
                acc[mi*4 + 1] = MFMA(a, b1, acc[mi*4 + 1]);
                acc[mi*4 + 2] = MFMA(a, b2, acc[mi*4 + 2]);
                acc[mi*4 + 3] = MFMA(a, b3, acc[mi*4 + 3]);
            }
            __builtin_amdgcn_s_setprio(0);
        }
    }

    // ---- acc -> WT (bf16, XOR-swizzled columns), rows are slice-local ----
#pragma unroll
    for (int mi = 0; mi < 2; ++mi)
#pragma unroll
        for (int rr = 0; rr < 4; ++rr)
#pragma unroll
            for (int r = 0; r < 4; ++r) {
                int row = 16*mi + 4*q + r;
                int col = (w*64 + 16*rr + c) ^ ((row & 7) << 3);
                WT[row*256 + col] = f2bf(acc[mi*4 + rr][r]);
                acc[mi*4 + rr][r] = 0.f;
            }
    __syncthreads();

    // ---- phase 2 (no barriers): wave w -> x' in [w*64, w*64+64) ----
    {
        int wm2 = w * 64;
#pragma unroll 2
        for (int kk = 0; kk < 8; ++kk) {
            int xb = kk*32;
            bf8 b[2];
#pragma unroll
            for (int ni = 0; ni < 2; ++ni) {
                int row = 16*ni + c;
                int col = (xb + 8*q) ^ ((row & 7) << 3);
                b[ni] = *(const bf8*)&WT[row*256 + col];
            }
            int sbase = 255 - wm2 - c + xb + 8*q;
            __builtin_amdgcn_s_setprio(1);
#pragma unroll
            for (int mi = 0; mi < 4; ++mi) {
                int s0 = sbase - 16*mi;  // a[jj] = M1[wm2+16mi+c][xb+8q+jj]
                bf8 a; uint* pa = (uint*)&a;
                pa[0] = arr[0][s0];     pa[1] = arr[0][s0 + 2];
                pa[2] = arr[0][s0 + 4]; pa[3] = arr[0][s0 + 6];
#pragma unroll
                for (int ni = 0; ni < 2; ++ni)
                    acc[mi*2 + ni] = MFMA(a, b[ni], acc[mi*2 + ni]);
            }
            __builtin_amdgcn_s_setprio(0);
        }

        // ---- epilogue: Y + D*u -> global ----
        float dh = Dv[h];
        float* yb_ = out + (size_t)bh * LL * LL;
#pragma unroll
        for (int mi = 0; mi < 4; ++mi)
#pragma unroll
            for (int ni = 0; ni < 2; ++ni)
#pragma unroll
                for (int r = 0; r < 4; ++r) {
                    int row = wm2 + 16*mi + 4*q + r;
                    int col = yq + 16*ni + c;
                    size_t o = (size_t)row * LL + col;
                    yb_[o] = acc[mi*2 + ni][r] + dh * ub[o];
                }
    }
}

extern "C" void kernel_launch(void* const* d_in, const int* in_sizes, int n_in,
                              void* d_out, int out_size, void* d_ws, size_t ws_size,
                              hipStream_t stream)
{
    const float* u       = (const float*)d_in[0];
    const float* D       = (const float*)d_in[1];
    const float* A_re0   = (const float*)d_in[2];
    const float* A_im0   = (const float*)d_in[3];
    const float* C_re0   = (const float*)d_in[4];
    const float* C_im0   = (const float*)d_in[5];
    const float* log_dt0 = (const float*)d_in[6];
    const float* A_re1   = (const float*)d_in[7];
    const float* A_im1   = (const float*)d_in[8];
    const float* C_re1   = (const float*)d_in[9];
    const float* C_im1   = (const float*)d_in[10];
    const float* log_dt1 = (const float*)d_in[11];
    float* out = (float*)d_out;

    uint* arrg = (uint*)d_ws;   // 2*128*512 u32 = 512 KB

    ssm_gen_fast<<<dim3(HH, 2), 512, 0, stream>>>(
        A_re0, A_im0, C_re0, C_im0, log_dt0,
        A_re1, A_im1, C_re1, C_im1, log_dt1, arrg);
    s4nd_one<<<2048, 256, 0, stream>>>(u, D, arrg, out);
}

// Round 10
// 74.807 us; speedup vs baseline: 1.0593x; 1.0593x over previous
//
#include <hip/hip_runtime.h>

#define HH 128
#define NN 64
#define LL 256

typedef __attribute__((ext_vector_type(8))) short bf8;
typedef __attribute__((ext_vector_type(4))) float f32x4;

__device__ inline ushort f2bf(float f) {
    uint x = __float_as_uint(f);
    return (ushort)((x + 0x7fffu + ((x >> 16) & 1u)) >> 16);
}
__device__ inline uint cvt_pk_bf16(float lo, float hi) {
    uint r;
    asm volatile("v_cvt_pk_bf16_f32 %0, %1, %2" : "=v"(r) : "v"(lo), "v"(hi));
    return r;
}
#define MFMA(a,b,c) __builtin_amdgcn_mfma_f32_16x16x32_bf16((a),(b),(c),0,0,0)

// Tap generation, hw trig, one block per (h, s). Packed pair-table out:
// arrg[(s*HH+h)*512 + i] = rev[i] | rev[i+1]<<16, rev[i] = kcat_s[h][511-i].
__global__ __launch_bounds__(512) void ssm_gen_fast(
    const float* __restrict__ A_re0, const float* __restrict__ A_im0,
    const float* __restrict__ C_re0, const float* __restrict__ C_im0,
    const float* __restrict__ log_dt0,
    const float* __restrict__ A_re1, const float* __restrict__ A_im1,
    const float* __restrict__ C_re1, const float* __restrict__ C_im1,
    const float* __restrict__ log_dt1,
    uint* __restrict__ arrg)
{
    __shared__ float4 par[128];
    __shared__ ushort rev[512];

    int tid = threadIdx.x;
    int h   = blockIdx.x;
    int s   = blockIdx.y;

    if (tid < 128) {
        int n  = tid & 63;
        int ch = tid >> 6;
        const float* Ar = s ? A_re1 : A_re0;
        const float* Ai = s ? A_im1 : A_im0;
        const float* Cr = s ? C_re1 : C_re0;
        const float* Ci = s ? C_im1 : C_im0;
        const float* Ld = s ? log_dt1 : log_dt0;
        float dt = __expf(Ld[h]);
        float ar = Ar[h*NN + n], ai = Ai[h*NN + n];
        float cr = Cr[(ch*HH + h)*NN + n], ci = Ci[(ch*HH + h)*NN + n];
        float xr = dt * ar, xi = dt * ai;
        float phr = xi * 0.15915494f;
        float phf = phr - floorf(phr);
        float sn = __sinf(6.2831853f * phf);
        float cs = __cosf(6.2831853f * phf);
        float e  = __expf(xr);
        float er = e*cs - 1.f, ei = e*sn;
        float inv = 1.f / (ar*ar + ai*ai);
        float dr = (er*ar + ei*ai) * inv;
        float di = (ei*ar - er*ai) * inv;
        float Kr = 2.f*(cr*dr - ci*di);
        float Ki = 2.f*(cr*di + ci*dr);
        par[tid] = (float4){ xr, xi * 0.15915494f, Kr, Ki };
    }
    __syncthreads();

    {
        int l  = tid & 255;
        int ch = tid >> 8;
        float lf = (float)l;
        int ri = ch ? (256 + l) : (255 - l);
        const float4* pb = &par[ch*64];
        float acc = 0.f;
        for (int n = 0; n < NN; ++n) {
            float4 p = pb[n];
            float mag = __expf(p.x * lf);
            float ph  = p.y * lf;
            float phf = ph - floorf(ph);
            float ang = 6.2831853f * phf;
            acc += p.z * (mag * __cosf(ang)) - p.w * (mag * __sinf(ang));
        }
        rev[ri] = f2bf(acc);
    }
    __syncthreads();

    uint lo = rev[tid];
    uint hi = (tid < 511) ? (uint)rev[tid + 1] : 0u;
    arrg[(s*HH + h)*512 + tid] = lo | (hi << 16);
}

// ph1: one kk-step of WT_sub[y'][x] = sum_y M2[y'][y]*U[x][y], sub = 64 y'-rows.
#define PH1_STEP(ACC, YOFF, KK) do {                                          \
    int yb_ = (KK)*32 + 8*q;                                                  \
    float4 f0a = *(const float4*)(rp0 + yb_), f0b = *(const float4*)(rp0 + yb_ + 4); \
    float4 f1a = *(const float4*)(rp1 + yb_), f1b = *(const float4*)(rp1 + yb_ + 4); \
    bf8 b0, b1; uint* p0 = (uint*)&b0; uint* p1 = (uint*)&b1;                 \
    p0[0]=cvt_pk_bf16(f0a.x,f0a.y); p0[1]=cvt_pk_bf16(f0a.z,f0a.w);           \
    p0[2]=cvt_pk_bf16(f0b.x,f0b.y); p0[3]=cvt_pk_bf16(f0b.z,f0b.w);           \
    p1[0]=cvt_pk_bf16(f1a.x,f1a.y); p1[1]=cvt_pk_bf16(f1a.z,f1a.w);           \
    p1[2]=cvt_pk_bf16(f1b.x,f1b.y); p1[3]=cvt_pk_bf16(f1b.z,f1b.w);           \
    int sb_ = 255 - (YOFF) - c + (KK)*32 + 8*q;                               \
    __builtin_amdgcn_s_setprio(1);                                            \
    _Pragma("unroll")                                                         \
    for (int mi = 0; mi < 4; ++mi) {                                          \
        int s0 = sb_ - 16*mi;                                                 \
        bf8 a; uint* pa = (uint*)&a;                                          \
        pa[0]=arr[1][s0]; pa[1]=arr[1][s0+2]; pa[2]=arr[1][s0+4]; pa[3]=arr[1][s0+6]; \
        ACC[mi*2+0] = MFMA(a, b0, ACC[mi*2+0]);                               \
        ACC[mi*2+1] = MFMA(a, b1, ACC[mi*2+1]);                               \
    }                                                                         \
    __builtin_amdgcn_s_setprio(0);                                            \
} while(0)

// ph2: one kk-step of Y[x'][y'_sub] = sum_x M1[x'][x]*WT_sub[y'][x].
#define PH2_STEP(ACC, WTBUF, KK) do {                                         \
    int xb_ = (KK)*32;                                                        \
    bf8 bb0, bb1;                                                             \
    {   int row = wn2 + c;                                                    \
        int col = (xb_ + 8*q) ^ ((row & 7) << 3);                             \
        bb0 = *(const bf8*)&WTBUF[row*264 + col];                             \
        row = wn2 + 16 + c;                                                   \
        col = (xb_ + 8*q) ^ ((row & 7) << 3);                                 \
        bb1 = *(const bf8*)&WTBUF[row*264 + col]; }                           \
    int sb2_ = 255 - wm2 - c + xb_ + 8*q;                                     \
    __builtin_amdgcn_s_setprio(1);                                            \
    _Pragma("unroll")                                                         \
    for (int mi = 0; mi < 4; ++mi) {                                          \
        int s0 = sb2_ - 16*mi;                                                \
        bf8 a; uint* pa = (uint*)&a;                                          \
        pa[0]=arr[0][s0]; pa[1]=arr[0][s0+2]; pa[2]=arr[0][s0+4]; pa[3]=arr[0][s0+6]; \
        ACC[mi*2+0] = MFMA(a, bb0, ACC[mi*2+0]);                              \
        ACC[mi*2+1] = MFMA(a, bb1, ACC[mi*2+1]);                              \
    }                                                                         \
    __builtin_amdgcn_s_setprio(0);                                            \
} while(0)

#define WT_WRITE(ACC, WTBUF) do {                                             \
    _Pragma("unroll")                                                         \
    for (int mi = 0; mi < 4; ++mi)                                            \
    _Pragma("unroll")                                                         \
    for (int ni = 0; ni < 2; ++ni)                                            \
    _Pragma("unroll")                                                         \
    for (int r = 0; r < 4; ++r) {                                             \
        int row = 16*mi + 4*q + r;                                            \
        int col = (w*32 + 16*ni + c) ^ ((row & 7) << 3);                      \
        WTBUF[row*264 + col] = f2bf(ACC[mi*2+ni][r]);                         \
        ACC[mi*2+ni][r] = 0.f;                                                \
    }                                                                         \
} while(0)

// Fused S4ND per (b, h, y-half), 512 threads / 8 waves, 2 blocks/CU.
// Sub-tile pipeline: ph1(a) -> [ph1(b) || ph2(a)] -> ph2(b), so HBM loads
// of ph1(b) overlap the LDS/MFMA work of ph2(a).
__global__ __launch_bounds__(512, 4) void s4nd_pipe(
    const float* __restrict__ u, const float* __restrict__ Dv,
    const uint* __restrict__ arrg, float* __restrict__ out)
{
    __shared__ ushort WTa[64 * 264];     // 33792 B
    __shared__ ushort WTb[64 * 264];     // 33792 B
    __shared__ uint   arr[2][512];       // 4096 B

    int tid = threadIdx.x;

    // XCD-pairing swizzle: both y-halves of a bh on the same XCD, adjacent.
    int j    = blockIdx.x;
    int xcd  = j & 7;
    int k    = j >> 3;
    int bh   = xcd * 32 + (k >> 1);
    int y0   = (k & 1) * 128;
    int h    = bh & (HH - 1);

    arr[0][tid] = arrg[h*512 + tid];
    arr[1][tid] = arrg[(HH + h)*512 + tid];
    __syncthreads();

    int lane = tid & 63;
    int w = tid >> 6;                 // 0..7
    int c = lane & 15, q = lane >> 4;
    int wm2 = (w >> 1) * 64;          // ph2 x' block
    int wn2 = (w & 1) * 32;           // ph2 y'-sub block

    const float* ub = u + (size_t)bh * LL * LL;
    const float* rp0 = ub + (size_t)(w*32 +  0 + c) * LL;
    const float* rp1 = ub + (size_t)(w*32 + 16 + c) * LL;

    f32x4 acc0[8], acc1[8], acc2[8];
#pragma unroll
    for (int i = 0; i < 8; ++i) {
        acc0[i] = (f32x4){0.f,0.f,0.f,0.f};
        acc1[i] = (f32x4){0.f,0.f,0.f,0.f};
        acc2[i] = (f32x4){0.f,0.f,0.f,0.f};
    }

    // ---- stage 1: ph1(a) -> acc0 ----
#pragma unroll 2
    for (int kk = 0; kk < 8; ++kk)
        PH1_STEP(acc0, y0, kk);
    WT_WRITE(acc0, WTa);              // also zeroes acc0
    __syncthreads();

    // ---- stage 2: ph1(b) (HBM) interleaved with ph2(a) (LDS/MFMA) ----
#pragma unroll 2
    for (int kk = 0; kk < 8; ++kk) {
        PH1_STEP(acc1, y0 + 64, kk);
        PH2_STEP(acc2, WTa, kk);
    }
    WT_WRITE(acc1, WTb);
    __syncthreads();

    // ---- epi-a u prefetch (lands under ph2(b)) ----
    float uprea[32];
#pragma unroll
    for (int mi = 0; mi < 4; ++mi)
#pragma unroll
        for (int r = 0; r < 4; ++r) {
            int row = wm2 + 16*mi + 4*q + r;
#pragma unroll
            for (int ni = 0; ni < 2; ++ni)
                uprea[(mi*4 + r)*2 + ni] = ub[(size_t)row*LL + y0 + wn2 + 16*ni + c];
        }

    // ---- stage 3: ph2(b) -> acc0 ----
#pragma unroll 2
    for (int kk = 0; kk < 8; ++kk)
        PH2_STEP(acc0, WTb, kk);

    // ---- epilogues ----
    float dh = Dv[h];
    float* yb2 = out + (size_t)bh * LL * LL;
#pragma unroll
    for (int mi = 0; mi < 4; ++mi)
#pragma unroll
        for (int ni = 0; ni < 2; ++ni)
#pragma unroll
            for (int r = 0; r < 4; ++r) {
                int row = wm2 + 16*mi + 4*q + r;
                int col = y0 + wn2 + 16*ni + c;
                yb2[(size_t)row*LL + col] =
                    acc2[mi*2 + ni][r] + dh * uprea[(mi*4 + r)*2 + ni];
            }
    float upreb[32];
#pragma unroll
    for (int mi = 0; mi < 4; ++mi)
#pragma unroll
        for (int r = 0; r < 4; ++r) {
            int row = wm2 + 16*mi + 4*q + r;
#pragma unroll
            for (int ni = 0; ni < 2; ++ni)
                upreb[(mi*4 + r)*2 + ni] = ub[(size_t)row*LL + y0 + 64 + wn2 + 16*ni + c];
        }
#pragma unroll
    for (int mi = 0; mi < 4; ++mi)
#pragma unroll
        for (int ni = 0; ni < 2; ++ni)
#pragma unroll
            for (int r = 0; r < 4; ++r) {
                int row = wm2 + 16*mi + 4*q + r;
                int col = y0 + 64 + wn2 + 16*ni + c;
                yb2[(size_t)row*LL + col] =
                    acc0[mi*2 + ni][r] + dh * upreb[(mi*4 + r)*2 + ni];
            }
}

extern "C" void kernel_launch(void* const* d_in, const int* in_sizes, int n_in,
                              void* d_out, int out_size, void* d_ws, size_t ws_size,
                              hipStream_t stream)
{
    const float* u       = (const float*)d_in[0];
    const float* D       = (const float*)d_in[1];
    const float* A_re0   = (const float*)d_in[2];
    const float* A_im0   = (const float*)d_in[3];
    const float* C_re0   = (const float*)d_in[4];
    const float* C_im0   = (const float*)d_in[5];
    const float* log_dt0 = (const float*)d_in[6];
    const float* A_re1   = (const float*)d_in[7];
    const float* A_im1   = (const float*)d_in[8];
    const float* C_re1   = (const float*)d_in[9];
    const float* C_im1   = (const float*)d_in[10];
    const float* log_dt1 = (const float*)d_in[11];
    float* out = (float*)d_out;

    uint* arrg = (uint*)d_ws;   // 2*128*512 u32 = 512 KB

    ssm_gen_fast<<<dim3(HH, 2), 512, 0, stream>>>(
        A_re0, A_im0, C_re0, C_im0, log_dt0,
        A_re1, A_im1, C_re1, C_im1, log_dt1, arrg);
    s4nd_pipe<<<512, 512, 0, stream>>>(u, D, arrg, out);
}

// Round 11
// 60.194 us; speedup vs baseline: 1.3165x; 1.2428x over previous
//
#include <hip/hip_runtime.h>

#define HH 128
#define NN 64
#define LL 256

typedef __attribute__((ext_vector_type(8))) short bf8;
typedef __attribute__((ext_vector_type(4))) float f32x4;

__device__ inline ushort f2bf(float f) {
    uint x = __float_as_uint(f);
    return (ushort)((x + 0x7fffu + ((x >> 16) & 1u)) >> 16);
}
__device__ inline uint cvt_pk_bf16(float lo, float hi) {
    uint r;
    asm volatile("v_cvt_pk_bf16_f32 %0, %1, %2" : "=v"(r) : "v"(lo), "v"(hi));
    return r;
}
#define MFMA(a,b,c) __builtin_amdgcn_mfma_f32_16x16x32_bf16((a),(b),(c),0,0,0)

// Tap generation, hw trig, one block per (h, s). Packed pair-table out:
// arrg[(s*HH+h)*512 + i] = rev[i] | rev[i+1]<<16, rev[i] = kcat_s[h][511-i].
__global__ __launch_bounds__(512) void ssm_gen_fast(
    const float* __restrict__ A_re0, const float* __restrict__ A_im0,
    const float* __restrict__ C_re0, const float* __restrict__ C_im0,
    const float* __restrict__ log_dt0,
    const float* __restrict__ A_re1, const float* __restrict__ A_im1,
    const float* __restrict__ C_re1, const float* __restrict__ C_im1,
    const float* __restrict__ log_dt1,
    uint* __restrict__ arrg)
{
    __shared__ float4 par[128];
    __shared__ ushort rev[512];

    int tid = threadIdx.x;
    int h   = blockIdx.x;
    int s   = blockIdx.y;

    if (tid < 128) {
        int n  = tid & 63;
        int ch = tid >> 6;
        const float* Ar = s ? A_re1 : A_re0;
        const float* Ai = s ? A_im1 : A_im0;
        const float* Cr = s ? C_re1 : C_re0;
        const float* Ci = s ? C_im1 : C_im0;
        const float* Ld = s ? log_dt1 : log_dt0;
        float dt = __expf(Ld[h]);
        float ar = Ar[h*NN + n], ai = Ai[h*NN + n];
        float cr = Cr[(ch*HH + h)*NN + n], ci = Ci[(ch*HH + h)*NN + n];
        float xr = dt * ar, xi = dt * ai;
        float phr = xi * 0.15915494f;
        float phf = phr - floorf(phr);
        float sn = __sinf(6.2831853f * phf);
        float cs = __cosf(6.2831853f * phf);
        float e  = __expf(xr);
        float er = e*cs - 1.f, ei = e*sn;
        float inv = 1.f / (ar*ar + ai*ai);
        float dr = (er*ar + ei*ai) * inv;
        float di = (ei*ar - er*ai) * inv;
        float Kr = 2.f*(cr*dr - ci*di);
        float Ki = 2.f*(cr*di + ci*dr);
        par[tid] = (float4){ xr, xi * 0.15915494f, Kr, Ki };
    }
    __syncthreads();

    {
        int l  = tid & 255;
        int ch = tid >> 8;
        float lf = (float)l;
        int ri = ch ? (256 + l) : (255 - l);
        const float4* pb = &par[ch*64];
        float acc = 0.f;
        for (int n = 0; n < NN; ++n) {
            float4 p = pb[n];
            float mag = __expf(p.x * lf);
            float ph  = p.y * lf;
            float phf = ph - floorf(ph);
            float ang = 6.2831853f * phf;
            acc += p.z * (mag * __cosf(ang)) - p.w * (mag * __sinf(ang));
        }
        rev[ri] = f2bf(acc);
    }
    __syncthreads();

    uint lo = rev[tid];
    uint hi = (tid < 511) ? (uint)rev[tid + 1] : 0u;
    arrg[(s*HH + h)*512 + tid] = lo | (hi << 16);
}

// Pass 1 (y-axis conv, streaming, no main-loop barriers):
// WT[y'][x] = sum_y M2[y'][y] * U[x][y], per (bh, y'-half).
// Output: bf16 xk-blocked global layout wt[bh][xk=x/32][y' 256][x%32].
__global__ __launch_bounds__(512, 4) void s4nd_p1(
    const float* __restrict__ u, const uint* __restrict__ arrg,
    ushort* __restrict__ wt)
{
    __shared__ ushort ep[128 * 264];      // 67584 B epilogue shuffle buffer
    __shared__ uint   arr2[512];          // M2 pair table

    int tid = threadIdx.x;
    int j    = blockIdx.x;
    int xcd  = j & 7;
    int k    = j >> 3;
    int bh   = xcd * 32 + (k >> 1);
    int y0   = (k & 1) * 128;
    int h    = bh & (HH - 1);

    arr2[tid] = arrg[(HH + h)*512 + tid];
    __syncthreads();

    int lane = tid & 63;
    int w = tid >> 6;                 // 0..7
    int c = lane & 15, q = lane >> 4;

    f32x4 acc[16];
#pragma unroll
    for (int i = 0; i < 16; ++i) acc[i] = (f32x4){0.f,0.f,0.f,0.f};

    const float* ub = u + (size_t)bh * LL * LL;
    const float* rp0 = ub + (size_t)(w*32 +  0 + c) * LL;
    const float* rp1 = ub + (size_t)(w*32 + 16 + c) * LL;

#pragma unroll 2
    for (int kk = 0; kk < 8; ++kk) {
        int yb = kk*32 + 8*q;
        float4 f0 = *(const float4*)(rp0 + yb);
        float4 f1 = *(const float4*)(rp0 + yb + 4);
        float4 f2 = *(const float4*)(rp1 + yb);
        float4 f3 = *(const float4*)(rp1 + yb + 4);
        bf8 b0, b1;
        uint* p0 = (uint*)&b0; uint* p1 = (uint*)&b1;
        p0[0] = cvt_pk_bf16(f0.x, f0.y); p0[1] = cvt_pk_bf16(f0.z, f0.w);
        p0[2] = cvt_pk_bf16(f1.x, f1.y); p0[3] = cvt_pk_bf16(f1.z, f1.w);
        p1[0] = cvt_pk_bf16(f2.x, f2.y); p1[1] = cvt_pk_bf16(f2.z, f2.w);
        p1[2] = cvt_pk_bf16(f3.x, f3.y); p1[3] = cvt_pk_bf16(f3.z, f3.w);
        int sbase = 255 - y0 - c + kk*32 + 8*q;
        __builtin_amdgcn_s_setprio(1);
#pragma unroll
        for (int mi = 0; mi < 8; ++mi) {
            int s0 = sbase - 16*mi;   // a[jj] = M2[y0+16mi+c][kk*32+8q+jj]
            bf8 a; uint* pa = (uint*)&a;
            pa[0] = arr2[s0];     pa[1] = arr2[s0 + 2];
            pa[2] = arr2[s0 + 4]; pa[3] = arr2[s0 + 6];
            acc[mi*2 + 0] = MFMA(a, b0, acc[mi*2 + 0]);
            acc[mi*2 + 1] = MFMA(a, b1, acc[mi*2 + 1]);
        }
        __builtin_amdgcn_s_setprio(0);
    }

    // acc -> ep (bf16)
#pragma unroll
    for (int mi = 0; mi < 8; ++mi)
#pragma unroll
        for (int ni = 0; ni < 2; ++ni)
#pragma unroll
            for (int r = 0; r < 4; ++r) {
                int row = 16*mi + 4*q + r;
                int col = w*32 + 16*ni + c;
                ep[row*264 + col] = f2bf(acc[mi*2 + ni][r]);
            }
    __syncthreads();

    // ep -> blocked global store: wt[bh][xk][y0+row][x%32]
    ushort* wb = wt + (size_t)bh * 8 * LL * 32;
#pragma unroll
    for (int it = 0; it < 8; ++it) {
        int e   = tid + 512*it;       // 0..4095
        int row = e >> 5;             // 0..127
        int ch  = e & 31;             // 32 uint4 per row
        int xk  = ch >> 2;            // 0..7
        int xi  = (ch & 3) * 8;       // u16 offset in panel row
        *(uint4*)(wb + ((size_t)(xk*LL) + y0 + row)*32 + xi) =
            *(const uint4*)&ep[row*264 + ch*8];
    }
}

// Pass 2 (x-axis conv, streaming, no barriers): per (bh, y'-quarter).
// Y[x'][y'] = sum_x M1[x'][x] * WT[y'][x] + D[h]*u[x'][y'].
// B-fragments read directly from blocked WT (16 full 64B lines per load).
__global__ __launch_bounds__(256, 4) void s4nd_p2(
    const ushort* __restrict__ wt, const float* __restrict__ u,
    const uint* __restrict__ arrg, const float* __restrict__ Dv,
    float* __restrict__ out)
{
    __shared__ uint arr1[512];            // M1 pair table

    int tid = threadIdx.x;
    int j    = blockIdx.x;
    int xcd  = j & 7;
    int k    = j >> 3;                    // 0..127
    int bh   = xcd * 32 + (k >> 2);       // same bh->XCD map as pass 1
    int yq   = (k & 3) * 64;              // y' quarter
    int h    = bh & (HH - 1);

    arr1[tid]       = arrg[h*512 + tid];
    arr1[tid + 256] = arrg[h*512 + tid + 256];
    __syncthreads();

    int lane = tid & 63;
    int w = tid >> 6;                 // 0..3
    int c = lane & 15, q = lane >> 4;
    int wm2 = w * 64;                 // x' block

    f32x4 acc[16];
#pragma unroll
    for (int i = 0; i < 16; ++i) acc[i] = (f32x4){0.f,0.f,0.f,0.f};

    const ushort* wb = wt + (size_t)bh * 8 * LL * 32;

#pragma unroll 2
    for (int kk = 0; kk < 8; ++kk) {
        bf8 b[4];
#pragma unroll
        for (int ni = 0; ni < 4; ++ni) {
            int gy = yq + 16*ni + c;
            b[ni] = *(const bf8*)(wb + (size_t)kk*8192 + gy*32 + 8*q);
        }
        int sbase = 255 - wm2 - c + kk*32 + 8*q;
        __builtin_amdgcn_s_setprio(1);
#pragma unroll
        for (int mi = 0; mi < 4; ++mi) {
            int s0 = sbase - 16*mi;   // a[jj] = M1[wm2+16mi+c][kk*32+8q+jj]
            bf8 a; uint* pa = (uint*)&a;
            pa[0] = arr1[s0];     pa[1] = arr1[s0 + 2];
            pa[2] = arr1[s0 + 4]; pa[3] = arr1[s0 + 6];
#pragma unroll
            for (int ni = 0; ni < 4; ++ni)
                acc[mi*4 + ni] = MFMA(a, b[ni], acc[mi*4 + ni]);
        }
        __builtin_amdgcn_s_setprio(0);
    }

    // epilogue: Y + D*u -> global
    float dh = Dv[h];
    const float* ub = u + (size_t)bh * LL * LL;
    float* yb_ = out + (size_t)bh * LL * LL;
#pragma unroll
    for (int mi = 0; mi < 4; ++mi)
#pragma unroll
        for (int ni = 0; ni < 4; ++ni)
#pragma unroll
            for (int r = 0; r < 4; ++r) {
                int row = wm2 + 16*mi + 4*q + r;
                int col = yq + 16*ni + c;
                size_t o = (size_t)row * LL + col;
                yb_[o] = acc[mi*4 + ni][r] + dh * ub[o];
            }
}

extern "C" void kernel_launch(void* const* d_in, const int* in_sizes, int n_in,
                              void* d_out, int out_size, void* d_ws, size_t ws_size,
                              hipStream_t stream)
{
    const float* u       = (const float*)d_in[0];
    const float* D       = (const float*)d_in[1];
    const float* A_re0   = (const float*)d_in[2];
    const float* A_im0   = (const float*)d_in[3];
    const float* C_re0   = (const float*)d_in[4];
    const float* C_im0   = (const float*)d_in[5];
    const float* log_dt0 = (const float*)d_in[6];
    const float* A_re1   = (const float*)d_in[7];
    const float* A_im1   = (const float*)d_in[8];
    const float* C_re1   = (const float*)d_in[9];
    const float* C_im1   = (const float*)d_in[10];
    const float* log_dt1 = (const float*)d_in[11];
    float* out = (float*)d_out;

    uint*   arrg = (uint*)d_ws;                 // 2*128*512 u32 = 512 KB
    ushort* wtb  = (ushort*)(arrg + 2*HH*512);  // 256*8*256*32 bf16 = 33.5 MB

    ssm_gen_fast<<<dim3(HH, 2), 512, 0, stream>>>(
        A_re0, A_im0, C_re0, C_im0, log_dt0,
        A_re1, A_im1, C_re1, C_im1, log_dt1, arrg);
    s4nd_p1<<<512, 512, 0, stream>>>(u, arrg, wtb);
    s4nd_p2<<<1024, 256, 0, stream>>>(wtb, u, arrg, D, out);
}

// Round 12
// 46.078 us; speedup vs baseline: 1.7198x; 1.3064x over previous
//
#include <hip/hip_runtime.h>

#define HH 128
#define NN 64
#define LL 256

typedef __attribute__((ext_vector_type(8))) short bf8;
typedef __attribute__((ext_vector_type(4))) float f32x4;

__device__ inline ushort f2bf(float f) {
    uint x = __float_as_uint(f);
    return (ushort)((x + 0x7fffu + ((x >> 16) & 1u)) >> 16);
}
__device__ inline uint cvt_pk_bf16(float lo, float hi) {
    uint r;
    asm volatile("v_cvt_pk_bf16_f32 %0, %1, %2" : "=v"(r) : "v"(lo), "v"(hi));
    return r;
}
#define MFMA(a,b,c) __builtin_amdgcn_mfma_f32_16x16x32_bf16((a),(b),(c),0,0,0)

// Tap generation, hw trig, one block per (h, s). Packed pair-table out:
// arrg[(s*HH+h)*512 + i] = rev[i] | rev[i+1]<<16, rev[i] = kcat_s[h][511-i].
__global__ __launch_bounds__(512) void ssm_gen_fast(
    const float* __restrict__ A_re0, const float* __restrict__ A_im0,
    const float* __restrict__ C_re0, const float* __restrict__ C_im0,
    const float* __restrict__ log_dt0,
    const float* __restrict__ A_re1, const float* __restrict__ A_im1,
    const float* __restrict__ C_re1, const float* __restrict__ C_im1,
    const float* __restrict__ log_dt1,
    uint* __restrict__ arrg)
{
    __shared__ float4 par[128];
    __shared__ ushort rev[512];

    int tid = threadIdx.x;
    int h   = blockIdx.x;
    int s   = blockIdx.y;

    if (tid < 128) {
        int n  = tid & 63;
        int ch = tid >> 6;
        const float* Ar = s ? A_re1 : A_re0;
        const float* Ai = s ? A_im1 : A_im0;
        const float* Cr = s ? C_re1 : C_re0;
        const float* Ci = s ? C_im1 : C_im0;
        const float* Ld = s ? log_dt1 : log_dt0;
        float dt = __expf(Ld[h]);
        float ar = Ar[h*NN + n], ai = Ai[h*NN + n];
        float cr = Cr[(ch*HH + h)*NN + n], ci = Ci[(ch*HH + h)*NN + n];
        float xr = dt * ar, xi = dt * ai;
        float phr = xi * 0.15915494f;
        float phf = phr - floorf(phr);
        float sn = __sinf(6.2831853f * phf);
        float cs = __cosf(6.2831853f * phf);
        float e  = __expf(xr);
        float er = e*cs - 1.f, ei = e*sn;
        float inv = 1.f / (ar*ar + ai*ai);
        float dr = (er*ar + ei*ai) * inv;
        float di = (ei*ar - er*ai) * inv;
        float Kr = 2.f*(cr*dr - ci*di);
        float Ki = 2.f*(cr*di + ci*dr);
        par[tid] = (float4){ xr, xi * 0.15915494f, Kr, Ki };
    }
    __syncthreads();

    {
        int l  = tid & 255;
        int ch = tid >> 8;
        float lf = (float)l;
        int ri = ch ? (256 + l) : (255 - l);
        const float4* pb = &par[ch*64];
        float acc = 0.f;
        for (int n = 0; n < NN; ++n) {
            float4 p = pb[n];
            float mag = __expf(p.x * lf);
            float ph  = p.y * lf;
            float phf = ph - floorf(ph);
            float ang = 6.2831853f * phf;
            acc += p.z * (mag * __cosf(ang)) - p.w * (mag * __sinf(ang));
        }
        rev[ri] = f2bf(acc);
    }
    __syncthreads();

    uint lo = rev[tid];
    uint hi = (tid < 511) ? (uint)rev[tid + 1] : 0u;
    arrg[(s*HH + h)*512 + tid] = lo | (hi << 16);
}

// Fused S4ND per (b, h, y-half), 512 threads / 8 waves, 2 blocks/CU.
// K6 geometry + (1) 2-deep load pipeline in ph1, (2) ph2 split into two
// ni-halves with early u-prefetch and spread stores.
__global__ __launch_bounds__(512, 4) void s4nd_v2(
    const float* __restrict__ u, const float* __restrict__ Dv,
    const uint* __restrict__ arrg, float* __restrict__ out)
{
    __shared__ ushort WT[128 * 264];      // 67584 B
    __shared__ uint   arr[2][512];        // 4096 B

    int tid = threadIdx.x;

    // XCD-pairing swizzle: both y-halves of a bh on the same XCD, adjacent.
    int j    = blockIdx.x;
    int xcd  = j & 7;
    int k    = j >> 3;
    int bh   = xcd * 32 + (k >> 1);
    int y0   = (k & 1) * 128;
    int h    = bh & (HH - 1);

    arr[0][tid] = arrg[h*512 + tid];
    arr[1][tid] = arrg[(HH + h)*512 + tid];
    __syncthreads();

    int lane = tid & 63;
    int w = tid >> 6;                 // 0..7
    int c = lane & 15, q = lane >> 4;

    f32x4 acc[16];
#pragma unroll
    for (int i = 0; i < 16; ++i) acc[i] = (f32x4){0.f,0.f,0.f,0.f};

    const float* ub = u + (size_t)bh * LL * LL;
    const float* rp0 = ub + (size_t)(w*32 +  0 + c) * LL;
    const float* rp1 = ub + (size_t)(w*32 + 16 + c) * LL;

    // ---- phase 1: 2-deep software pipeline, no barriers ----
    float4 A0, A1, A2, A3, B0, B1, B2, B3;
    {
        int yb = 8*q;
        A0 = *(const float4*)(rp0 + yb); A1 = *(const float4*)(rp0 + yb + 4);
        A2 = *(const float4*)(rp1 + yb); A3 = *(const float4*)(rp1 + yb + 4);
    }
#pragma unroll
    for (int kk = 0; kk < 8; ++kk) {
        if (kk < 7) {
            int ybn = (kk + 1)*32 + 8*q;
            B0 = *(const float4*)(rp0 + ybn); B1 = *(const float4*)(rp0 + ybn + 4);
            B2 = *(const float4*)(rp1 + ybn); B3 = *(const float4*)(rp1 + ybn + 4);
        }
        bf8 b0, b1;
        uint* p0 = (uint*)&b0; uint* p1 = (uint*)&b1;
        p0[0] = cvt_pk_bf16(A0.x, A0.y); p0[1] = cvt_pk_bf16(A0.z, A0.w);
        p0[2] = cvt_pk_bf16(A1.x, A1.y); p0[3] = cvt_pk_bf16(A1.z, A1.w);
        p1[0] = cvt_pk_bf16(A2.x, A2.y); p1[1] = cvt_pk_bf16(A2.z, A2.w);
        p1[2] = cvt_pk_bf16(A3.x, A3.y); p1[3] = cvt_pk_bf16(A3.z, A3.w);
        int sbase = 255 - y0 - c + kk*32 + 8*q;
        __builtin_amdgcn_s_setprio(1);
#pragma unroll
        for (int mi = 0; mi < 8; ++mi) {
            int s0 = sbase - 16*mi;   // a[jj] = M2[y0+16mi+c][kk*32+8q+jj]
            bf8 a; uint* pa = (uint*)&a;
            pa[0] = arr[1][s0];     pa[1] = arr[1][s0 + 2];
            pa[2] = arr[1][s0 + 4]; pa[3] = arr[1][s0 + 6];
            acc[mi*2 + 0] = MFMA(a, b0, acc[mi*2 + 0]);
            acc[mi*2 + 1] = MFMA(a, b1, acc[mi*2 + 1]);
        }
        __builtin_amdgcn_s_setprio(0);
        A0 = B0; A1 = B1; A2 = B2; A3 = B3;
    }

    // ---- acc -> WT (bf16, XOR-swizzled columns) ----
#pragma unroll
    for (int mi = 0; mi < 8; ++mi)
#pragma unroll
        for (int ni = 0; ni < 2; ++ni)
#pragma unroll
            for (int r = 0; r < 4; ++r) {
                int row = 16*mi + 4*q + r;
                int col = (w*32 + 16*ni + c) ^ ((row & 7) << 3);
                WT[row*264 + col] = f2bf(acc[mi*2 + ni][r]);
                acc[mi*2 + ni][r] = 0.f;
            }
    __syncthreads();

    // ---- phase 2: two ni-halves, u-prefetch early, stores spread ----
    int wm2 = (w >> 1) * 64, wn2 = (w & 1) * 64;
    float dh = Dv[h];
    float* yb_ = out + (size_t)bh * LL * LL;

#pragma unroll
    for (int half = 0; half < 2; ++half) {
        int nb = wn2 + half*32;       // y'-base of this half (2 ni blocks)

        // prefetch epilogue u for this half (lands under the kk loop)
        float uh[32];
#pragma unroll
        for (int mi = 0; mi < 4; ++mi)
#pragma unroll
            for (int r = 0; r < 4; ++r) {
                int row = wm2 + 16*mi + 4*q + r;
#pragma unroll
                for (int ni = 0; ni < 2; ++ni)
                    uh[(mi*4 + r)*2 + ni] = ub[(size_t)row*LL + y0 + nb + 16*ni + c];
            }

#pragma unroll
        for (int kk = 0; kk < 8; ++kk) {
            int xb = kk*32;
            bf8 b0, b1;
            {
                int row = nb + c;
                int col = (xb + 8*q) ^ ((row & 7) << 3);
                b0 = *(const bf8*)&WT[row*264 + col];
                row = nb + 16 + c;
                col = (xb + 8*q) ^ ((row & 7) << 3);
                b1 = *(const bf8*)&WT[row*264 + col];
            }
            int sbase = 255 - wm2 - c + xb + 8*q;
            __builtin_amdgcn_s_setprio(1);
#pragma unroll
            for (int mi = 0; mi < 4; ++mi) {
                int s0 = sbase - 16*mi;  // a[jj] = M1[wm2+16mi+c][xb+8q+jj]
                bf8 a; uint* pa = (uint*)&a;
                pa[0] = arr[0][s0];     pa[1] = arr[0][s0 + 2];
                pa[2] = arr[0][s0 + 4]; pa[3] = arr[0][s0 + 6];
                acc[mi*2 + 0] = MFMA(a, b0, acc[mi*2 + 0]);
                acc[mi*2 + 1] = MFMA(a, b1, acc[mi*2 + 1]);
            }
            __builtin_amdgcn_s_setprio(0);
        }

        // store this half (+D*u), reset acc
#pragma unroll
        for (int mi = 0; mi < 4; ++mi)
#pragma unroll
            for (int ni = 0; ni < 2; ++ni)
#pragma unroll
                for (int r = 0; r < 4; ++r) {
                    int row = wm2 + 16*mi + 4*q + r;
                    int col = y0 + nb + 16*ni + c;
                    yb_[(size_t)row*LL + col] =
                        acc[mi*2 + ni][r] + dh * uh[(mi*4 + r)*2 + ni];
                    acc[mi*2 + ni][r] = 0.f;
                }
    }
}

extern "C" void kernel_launch(void* const* d_in, const int* in_sizes, int n_in,
                              void* d_out, int out_size, void* d_ws, size_t ws_size,
                              hipStream_t stream)
{
    const float* u       = (const float*)d_in[0];
    const float* D       = (const float*)d_in[1];
    const float* A_re0   = (const float*)d_in[2];
    const float* A_im0   = (const float*)d_in[3];
    const float* C_re0   = (const float*)d_in[4];
    const float* C_im0   = (const float*)d_in[5];
    const float* log_dt0 = (const float*)d_in[6];
    const float* A_re1   = (const float*)d_in[7];
    const float* A_im1   = (const float*)d_in[8];
    const float* C_re1   = (const float*)d_in[9];
    const float* C_im1   = (const float*)d_in[10];
    const float* log_dt1 = (const float*)d_in[11];
    float* out = (float*)d_out;

    uint* arrg = (uint*)d_ws;   // 2*128*512 u32 = 512 KB

    ssm_gen_fast<<<dim3(HH, 2), 512, 0, stream>>>(
        A_re0, A_im0, C_re0, C_im0, log_dt0,
        A_re1, A_im1, C_re1, C_im1, log_dt1, arrg);
    s4nd_v2<<<512, 512, 0, stream>>>(u, D, arrg, out);
}

// Round 13
// 44.159 us; speedup vs baseline: 1.7945x; 1.0435x over previous
//
#include <hip/hip_runtime.h>

#define HH 128
#define NN 64
#define LL 256
#define WP 280   // u16 pitch: 140 dwords = 12 mod 32 -> conflict-free b128 rows

typedef __attribute__((ext_vector_type(8))) short bf8;
typedef __attribute__((ext_vector_type(4))) float f32x4;

__device__ inline ushort f2bf(float f) {
    uint x = __float_as_uint(f);
    return (ushort)((x + 0x7fffu + ((x >> 16) & 1u)) >> 16);
}
__device__ inline uint cvt_pk_bf16(float lo, float hi) {
    uint r;
    asm volatile("v_cvt_pk_bf16_f32 %0, %1, %2" : "=v"(r) : "v"(lo), "v"(hi));
    return r;
}
#define MFMA(a,b,c) __builtin_amdgcn_mfma_f32_16x16x32_bf16((a),(b),(c),0,0,0)

// Tap generation, hw trig, one block per (h, s); n-loop split 2-way + LDS reduce.
// arrg[(s*HH+h)*512 + i] = rev[i] | rev[i+1]<<16, rev[i] = kcat_s[h][511-i].
__global__ __launch_bounds__(512) void ssm_gen_fast(
    const float* __restrict__ A_re0, const float* __restrict__ A_im0,
    const float* __restrict__ C_re0, const float* __restrict__ C_im0,
    const float* __restrict__ log_dt0,
    const float* __restrict__ A_re1, const float* __restrict__ A_im1,
    const float* __restrict__ C_re1, const float* __restrict__ C_im1,
    const float* __restrict__ log_dt1,
    uint* __restrict__ arrg)
{
    __shared__ float4 par[128];       // (ch,n) -> {xr, xi_rev, Kr2, Ki2}
    __shared__ float  red[512];       // partial sums
    __shared__ ushort rev[512];

    int tid = threadIdx.x;
    int h   = blockIdx.x;
    int s   = blockIdx.y;

    if (tid < 128) {
        int n  = tid & 63;
        int ch = tid >> 6;
        const float* Ar = s ? A_re1 : A_re0;
        const float* Ai = s ? A_im1 : A_im0;
        const float* Cr = s ? C_re1 : C_re0;
        const float* Ci = s ? C_im1 : C_im0;
        const float* Ld = s ? log_dt1 : log_dt0;
        float dt = __expf(Ld[h]);
        float ar = Ar[h*NN + n], ai = Ai[h*NN + n];
        float cr = Cr[(ch*HH + h)*NN + n], ci = Ci[(ch*HH + h)*NN + n];
        float xr = dt * ar, xi = dt * ai;
        float phr = xi * 0.15915494f;
        float phf = phr - floorf(phr);
        float sn = __sinf(6.2831853f * phf);
        float cs = __cosf(6.2831853f * phf);
        float e  = __expf(xr);
        float er = e*cs - 1.f, ei = e*sn;
        float inv = 1.f / (ar*ar + ai*ai);
        float dr = (er*ar + ei*ai) * inv;
        float di = (ei*ar - er*ai) * inv;
        float Kr = 2.f*(cr*dr - ci*di);
        float Ki = 2.f*(cr*di + ci*dr);
        par[tid] = (float4){ xr, xi * 0.15915494f, Kr, Ki };
    }
    __syncthreads();

    // thread = (nh, ch, l): 512 = 2 ch * 256 l, each does 32 n per nh pass
    {
        int l  = tid & 255;
        int ch = tid >> 8;        // 0..1
        float lf = (float)l;
#pragma unroll
        for (int nh = 0; nh < 2; ++nh) {
            // nh handled by looping: split 64 into two 32-chunks; partial in red
            const float4* pb = &par[ch*64 + nh*32];
            float acc = 0.f;
            for (int n = 0; n < 32; ++n) {
                float4 p = pb[n];
                float mag = __expf(p.x * lf);
                float ph  = p.y * lf;
                float phf = ph - floorf(ph);
                float ang = 6.2831853f * phf;
                acc += p.z * (mag * __cosf(ang)) - p.w * (mag * __sinf(ang));
            }
            if (nh == 0) red[tid] = acc;
            else {
                int ri = ch ? (256 + l) : (255 - l);
                rev[ri] = f2bf(red[tid] + acc);
            }
        }
    }
    __syncthreads();

    uint lo = rev[tid];
    uint hi = (tid < 511) ? (uint)rev[tid + 1] : 0u;
    arrg[(s*HH + h)*512 + tid] = lo | (hi << 16);
}

// Fused S4ND per (b, h, y-half), 512 threads / 8 waves, 2 blocks/CU.
__global__ __launch_bounds__(512, 4) void s4nd_v3(
    const float* __restrict__ u, const float* __restrict__ Dv,
    const uint* __restrict__ arrg, float* __restrict__ out)
{
    __shared__ ushort WT[128 * WP];       // 71680 B
    __shared__ uint   arr[2][512];        // 4096 B

    int tid = threadIdx.x;

    // XCD-pairing swizzle: both y-halves of a bh on the same XCD, adjacent.
    int j    = blockIdx.x;
    int xcd  = j & 7;
    int k    = j >> 3;
    int bh   = xcd * 32 + (k >> 1);
    int y0   = (k & 1) * 128;
    int h    = bh & (HH - 1);

    arr[0][tid] = arrg[h*512 + tid];
    arr[1][tid] = arrg[(HH + h)*512 + tid];
    __syncthreads();

    int lane = tid & 63;
    int w = tid >> 6;                 // 0..7
    int c = lane & 15, q = lane >> 4;

    f32x4 acc[16];
#pragma unroll
    for (int i = 0; i < 16; ++i) acc[i] = (f32x4){0.f,0.f,0.f,0.f};

    const float* ub = u + (size_t)bh * LL * LL;
    const float* rp0 = ub + (size_t)(w*32 +  0 + c) * LL;
    const float* rp1 = ub + (size_t)(w*32 + 16 + c) * LL;

    // ---- phase 1: forced 2-deep load pipeline, no barriers ----
    float4 A0, A1, A2, A3, B0, B1, B2, B3;
    {
        int yb = 8*q;
        A0 = *(const float4*)(rp0 + yb); A1 = *(const float4*)(rp0 + yb + 4);
        A2 = *(const float4*)(rp1 + yb); A3 = *(const float4*)(rp1 + yb + 4);
    }
#pragma unroll
    for (int kk = 0; kk < 8; ++kk) {
        if (kk < 7) {
            int ybn = (kk + 1)*32 + 8*q;
            B0 = *(const float4*)(rp0 + ybn); B1 = *(const float4*)(rp0 + ybn + 4);
            B2 = *(const float4*)(rp1 + ybn); B3 = *(const float4*)(rp1 + ybn + 4);
        }
        // pin the issue point: nothing below may move above, loads stay here
        __builtin_amdgcn_sched_barrier(0);
        bf8 b0, b1;
        uint* p0 = (uint*)&b0; uint* p1 = (uint*)&b1;
        p0[0] = cvt_pk_bf16(A0.x, A0.y); p0[1] = cvt_pk_bf16(A0.z, A0.w);
        p0[2] = cvt_pk_bf16(A1.x, A1.y); p0[3] = cvt_pk_bf16(A1.z, A1.w);
        p1[0] = cvt_pk_bf16(A2.x, A2.y); p1[1] = cvt_pk_bf16(A2.z, A2.w);
        p1[2] = cvt_pk_bf16(A3.x, A3.y); p1[3] = cvt_pk_bf16(A3.z, A3.w);
        int sbase = 255 - y0 - c + kk*32 + 8*q;
        __builtin_amdgcn_s_setprio(1);
#pragma unroll
        for (int mi = 0; mi < 8; ++mi) {
            int s0 = sbase - 16*mi;   // a[jj] = M2[y0+16mi+c][kk*32+8q+jj]
            bf8 a; uint* pa = (uint*)&a;
            pa[0] = arr[1][s0];     pa[1] = arr[1][s0 + 2];
            pa[2] = arr[1][s0 + 4]; pa[3] = arr[1][s0 + 6];
            acc[mi*2 + 0] = MFMA(a, b0, acc[mi*2 + 0]);
            acc[mi*2 + 1] = MFMA(a, b1, acc[mi*2 + 1]);
        }
        __builtin_amdgcn_s_setprio(0);
        A0 = B0; A1 = B1; A2 = B2; A3 = B3;
    }

    // ---- acc -> WT (bf16, linear cols, WP pitch handles banks) ----
#pragma unroll
    for (int mi = 0; mi < 8; ++mi)
#pragma unroll
        for (int ni = 0; ni < 2; ++ni)
#pragma unroll
            for (int r = 0; r < 4; ++r) {
                int row = 16*mi + 4*q + r;
                int col = w*32 + 16*ni + c;
                WT[row*WP + col] = f2bf(acc[mi*2 + ni][r]);
                acc[mi*2 + ni][r] = 0.f;
            }
    __syncthreads();

    // ---- phase 2: two ni-halves, u-prefetch early, stores spread ----
    int wm2 = (w >> 1) * 64, wn2 = (w & 1) * 64;
    float dh = Dv[h];
    float* yb_ = out + (size_t)bh * LL * LL;

#pragma unroll
    for (int half = 0; half < 2; ++half) {
        int nb = wn2 + half*32;       // y'-base of this half (2 ni blocks)

        // prefetch epilogue u for this half (lands under the kk loop)
        float uh[32];
#pragma unroll
        for (int mi = 0; mi < 4; ++mi)
#pragma unroll
            for (int r = 0; r < 4; ++r) {
                int row = wm2 + 16*mi + 4*q + r;
#pragma unroll
                for (int ni = 0; ni < 2; ++ni)
                    uh[(mi*4 + r)*2 + ni] = ub[(size_t)row*LL + y0 + nb + 16*ni + c];
            }

#pragma unroll
        for (int kk = 0; kk < 8; ++kk) {
            int xb = kk*32;
            bf8 b0, b1;
            b0 = *(const bf8*)&WT[(nb + c)*WP + xb + 8*q];
            b1 = *(const bf8*)&WT[(nb + 16 + c)*WP + xb + 8*q];
            int sbase = 255 - wm2 - c + xb + 8*q;
            __builtin_amdgcn_s_setprio(1);
#pragma unroll
            for (int mi = 0; mi < 4; ++mi) {
                int s0 = sbase - 16*mi;  // a[jj] = M1[wm2+16mi+c][xb+8q+jj]
                bf8 a; uint* pa = (uint*)&a;
                pa[0] = arr[0][s0];     pa[1] = arr[0][s0 + 2];
                pa[2] = arr[0][s0 + 4]; pa[3] = arr[0][s0 + 6];
                acc[mi*2 + 0] = MFMA(a, b0, acc[mi*2 + 0]);
                acc[mi*2 + 1] = MFMA(a, b1, acc[mi*2 + 1]);
            }
            __builtin_amdgcn_s_setprio(0);
        }

        // store this half (+D*u), reset acc
#pragma unroll
        for (int mi = 0; mi < 4; ++mi)
#pragma unroll
            for (int ni = 0; ni < 2; ++ni)
#pragma unroll
                for (int r = 0; r < 4; ++r) {
                    int row = wm2 + 16*mi + 4*q + r;
                    int col = y0 + nb + 16*ni + c;
                    yb_[(size_t)row*LL + col] =
                        acc[mi*2 + ni][r] + dh * uh[(mi*4 + r)*2 + ni];
                    acc[mi*2 + ni][r] = 0.f;
                }
    }
}

extern "C" void kernel_launch(void* const* d_in, const int* in_sizes, int n_in,
                              void* d_out, int out_size, void* d_ws, size_t ws_size,
                              hipStream_t stream)
{
    const float* u       = (const float*)d_in[0];
    const float* D       = (const float*)d_in[1];
    const float* A_re0   = (const float*)d_in[2];
    const float* A_im0   = (const float*)d_in[3];
    const float* C_re0   = (const float*)d_in[4];
    const float* C_im0   = (const float*)d_in[5];
    const float* log_dt0 = (const float*)d_in[6];
    const float* A_re1   = (const float*)d_in[7];
    const float* A_im1   = (const float*)d_in[8];
    const float* C_re1   = (const float*)d_in[9];
    const float* C_im1   = (const float*)d_in[10];
    const float* log_dt1 = (const float*)d_in[11];
    float* out = (float*)d_out;

    uint* arrg = (uint*)d_ws;   // 2*128*512 u32 = 512 KB

    ssm_gen_fast<<<dim3(HH, 2), 512, 0, stream>>>(
        A_re0, A_im0, C_re0, C_im0, log_dt0,
        A_re1, A_im1, C_re1, C_im1, log_dt1, arrg);
    s4nd_v3<<<512, 512, 0, stream>>>(u, D, arrg, out);
}